// Round 16
// baseline (1071.518 us; speedup 1.0000x reference)
//
#include <hip/hip_runtime.h>
#include <stdio.h>

// ---------------------------------------------------------------------------
// Masked-LSTM LM:  out = softmax(states @ Wd + bd)
//
// Round-16 = r15 (k4n2 + coalesced untagged entries + flags, 1.06ms) +
//  * xz gather pipelined one step ahead: tok_{t+1} issued at iter top
//    (hides under poll sweep 1), embW_{t+1} issued after the MFMA region
//    (needed ~1500cy later) => the poll's vmcnt(0) no longer drains a
//    cold tok->embW chain (~300-500cy off the serial path).
//  * data fetch split: 8 loads -> vmcnt(4) -> MFMA kk0-3 -> vmcnt(0) ->
//    MFMA kk4-7 (separate wait-asms + sched_barrier(0) per rule #18)
//    overlaps first-half MFMA with second-half load return (~100cy).
//  * Protocol unchanged (r12/r13/r15-proven): producer plain stores ->
//    dirty in local XCD L2; consumer sc0 sc1 loads bypass L1, served
//    fresh by L2. Per-wave flags after vmcnt(0). ONE block barrier/step.
//  * Canary: absmax must stay ~6.103516e-5.
// ---------------------------------------------------------------------------

typedef _Float16 f16;
typedef f16 f16x8 __attribute__((ext_vector_type(8)));
typedef f16 f16x4 __attribute__((ext_vector_type(4)));
typedef float f32x4 __attribute__((ext_vector_type(4)));
typedef unsigned int u32;
typedef u32 u32x4 __attribute__((ext_vector_type(4)));

static constexpr int V = 128, E = 256, H = 1024, NB = 128, T = 512, FH = 4096;

// workspace layout (bytes)
static constexpr size_t OFF_CTRL = 0;        // [0]=initctr, [8..15]=xcdcnt, [1024..]=flags[2048]
static constexpr size_t SZ_CTRL  = 16384;
static constexpr size_t OFF_HB0  = SZ_CTRL;  // entries [bg8][kg4][l4 4][kk8][b16] f16x8
static constexpr size_t SZ_HB    = (size_t)16384 * 16;         // 256 KB
static constexpr size_t OFF_HB1  = OFF_HB0 + SZ_HB;
static constexpr size_t OFF_EMBW = OFF_HB1 + SZ_HB;            // 2 MB f32
static constexpr size_t SZ_EMBW  = (size_t)V * FH * 4;
static constexpr size_t OFF_UF   = OFF_EMBW + SZ_EMBW;         // 8 MB f16
static constexpr size_t SZ_UF    = (size_t)H * FH * 2;
static constexpr size_t OFF_WD   = OFF_UF + SZ_UF;             // 256 KB f16
static constexpr size_t SZ_WD    = (size_t)H * V * 2;
static constexpr size_t OFF_ST   = OFF_WD + SZ_WD;             // 128 MB f16
static constexpr size_t SZ_ST    = (size_t)NB * T * H * 2;
static constexpr size_t WS_NEED  = OFF_ST + SZ_ST;             // ~139 MB

// ---------------------------------------------------------------------------
__device__ __forceinline__ float fast_sigmoid(float x) {
  return __builtin_amdgcn_rcpf(1.f + __expf(-x));
}
__device__ __forceinline__ float fast_tanh(float x) {
  const float e = __expf(2.f * x);
  return (e - 1.f) * __builtin_amdgcn_rcpf(e + 1.f);
}

// ---------------------------------------------------------------------------
// embW[v][j] = b[j] + sum_e emb[v][e] * W[e][j]
__global__ void prep_embW(const float* __restrict__ emb, const float* __restrict__ W,
                          const float* __restrict__ bias, float* __restrict__ embW) {
  const int j  = blockIdx.x * 16 + (threadIdx.x & 15);
  const int vg = threadIdx.x >> 4;
  float a[8];
  const float bj = bias[j];
#pragma unroll
  for (int r = 0; r < 8; ++r) a[r] = bj;
  for (int e = 0; e < E; ++e) {
    const float wv = W[(size_t)e * FH + j];
#pragma unroll
    for (int r = 0; r < 8; ++r) a[r] += emb[(size_t)(vg * 8 + r) * E + e] * wv;
  }
#pragma unroll
  for (int r = 0; r < 8; ++r) embW[(size_t)(vg * 8 + r) * FH + j] = a[r];
}

// ---------------------------------------------------------------------------
// U (f32 [1024][4096]) -> fp16 B-fragment chunks, coalesced reads.
// Wave (kg=w&3, ng=w>>2): Bf[nt][kk] = up[(nt*8+kk)*64 + lane], where
//   k = kg*256 + kk*32 + (lane>>4)*8 + e
//   n = ng*64 + nt*16 + (lane&15);  ucol = (n>>5)*1024 + cg*32 + (n&31)
__global__ void prep_U(const float* __restrict__ U, f16* __restrict__ uf) {
  const int q  = blockIdx.x * 256 + threadIdx.x;      // 0..524287
  const int k  = q >> 9;
  const int j0 = (q & 511) * 8;
  const int kg = k >> 8, kk = (k >> 5) & 7, l4s = (k >> 3) & 3, es = k & 7;
  const float* row = U + (size_t)k * FH + j0;
#pragma unroll
  for (int i = 0; i < 8; ++i) {
    const int j = j0 + i;
    const int g = j >> 10, cg = (j >> 5) & 31, s = j & 31;
    const int n = g * 32 + s;
    const int ng = n >> 6, nt = (n >> 4) & 3, l15 = n & 15;
    const int w = ng * 4 + kg;
    const int chunk = ((cg * 8 + w) * 4 + nt) * 8 + kk;
    uf[((size_t)chunk * 64 + l4s * 16 + l15) * 8 + es] = (f16)row[i];
  }
}

// ---------------------------------------------------------------------------
// Wd (f32 [1024][128]) -> fp16 fragment chunks [nt 8][kk 32][lane 64][e 8]
__global__ void prep_Wd(const float* __restrict__ Wd, f16* __restrict__ wd) {
  const int c = blockIdx.x * 256 + threadIdx.x;       // 0..16383
  const int lane = c & 63, kk = (c >> 6) & 31, nt = c >> 11;
  const int k0 = kk * 32 + ((lane >> 4) << 3);
  const int v  = nt * 16 + (lane & 15);
  f16x8 o;
#pragma unroll
  for (int e = 0; e < 8; ++e) o[e] = (f16)Wd[(size_t)(k0 + e) * V + v];
  ((f16x8*)wd)[c] = o;
}

// ---------------------------------------------------------------------------
// entry (16B, f16x8): h[j..j+7], j = kg*256 + kk*32 + l4*8, batch b.
//   idx(bg,kg,l4,kk,b16) = (((bg*4 + kg)*4 + l4)*8 + kk)*16 + b16
// Producer block cg: kg=cg>>3, kk=cg&7, l4=l_g>>3 (8 threads/entry).
// Consumer wave (kg): 8 loads at base + kk*256B, lane stride 16B.
// flags idx(bg,cg,pw) = (bg*4 + (cg>>3))*64 + (cg&7)*8 + pw; value t+1.
__global__ __launch_bounds__(512, 2) void lstm_kernel(
    const int*   __restrict__ tok,    // [128][512]
    const float* __restrict__ embW,   // [128][4096]
    const f16x8* __restrict__ Ufrag,
    u32x4* hB0, u32x4* hB1,
    f16* __restrict__ st,             // states frag [t*8+bg][kc 128][m 16][e 8]
    int* ctrl)
{
  const int blk = blockIdx.x;
  const int tid = threadIdx.x;
  const int w = tid >> 6, lane = tid & 63;
  const int l15 = lane & 15, l4 = lane >> 4;
  const int kg = w & 3, ng = w >> 2;

  int* initctr = ctrl;
  int* xcdcnt  = ctrl + 8;
  int* flags   = ctrl + 1024;         // [bg 8][kg 4][c8 8][pw 8]

  // 82560B (>80KB => 1 block/CU => all 256 blocks co-resident).
  __shared__ f16 zph[2][8][129][20];
  __shared__ int s_bg, s_cg, s_fast;

  // ---- one-time election: discover placement, assign XCD-local roles ----
  const int myxcd = (int)(__builtin_amdgcn_s_getreg(6164) & 15); // HW_REG_XCC_ID
  if (tid == 0) {
    const int rank = __hip_atomic_fetch_add(&xcdcnt[myxcd & 7], 1,
                                            __ATOMIC_RELAXED, __HIP_MEMORY_SCOPE_AGENT);
    __hip_atomic_fetch_add(initctr, 1, __ATOMIC_RELEASE, __HIP_MEMORY_SCOPE_AGENT);
    int spins = 0;
    while (__hip_atomic_load(initctr, __ATOMIC_RELAXED, __HIP_MEMORY_SCOPE_AGENT) < 256) {
      __builtin_amdgcn_s_sleep(8);
      if (++spins > (1 << 15)) break;       // watchdog: never hang
    }
    const int total = __hip_atomic_load(initctr, __ATOMIC_ACQUIRE,
                                        __HIP_MEMORY_SCOPE_AGENT);
    int fast = (total >= 256) ? 1 : 0;
    for (int i = 0; i < 8; ++i)
      fast &= (__hip_atomic_load(&xcdcnt[i], __ATOMIC_RELAXED,
                                 __HIP_MEMORY_SCOPE_AGENT) == 32) ? 1 : 0;
    s_fast = fast;
    s_bg = fast ? (myxcd & 7) : (blk & 7);  // fast: bg-group == one XCD
    s_cg = fast ? rank        : (blk >> 3);
  }
  __syncthreads();
  const int FAST = s_fast;
  const int bg = s_bg, cg = s_cg;

  // persistent U fragments: wave (kg,ng) -> k [kg*256,+256), n [ng*64,+64)
  f16x8 Bf[4][8];
  {
    const f16x8* up = Ufrag + (size_t)(cg * 8 + w) * 2048;
#pragma unroll
    for (int nt = 0; nt < 4; ++nt)
#pragma unroll
      for (int kk = 0; kk < 8; ++kk)
        Bf[nt][kk] = up[(nt * 8 + kk) * 64 + lane];
  }

  // gate-phase assignment: one (batch-row, hcol) per thread
  const int m_g = tid >> 5;            // 0..15
  const int l_g = tid & 31;            // 0..31
  const int b_g = bg * 16 + m_g;
  const int j_g = cg * 32 + l_g;       // hcol this thread produces
  const int kg_s = cg >> 3, kk_s = cg & 7, l4_s = l_g >> 3;
  const int pidx = (((bg * 4 + kg_s) * 4 + l4_s) * 8 + kk_s) * 16 + m_g;
  int* pflag = flags + (bg * 4 + kg_s) * 64 + kk_s * 8 + w;
  float c_st = 0.f, h_st = 0.f;

  // consumer: 8 coalesced entries (kk 0..7 at offset kk*256B); 64 flags
  const int cbase = (((bg * 4 + kg) * 4 + l4) * 8) * 16 + l15;
  const int* fpoll = flags + (bg * 4 + kg) * 64 + lane;

  const size_t stbase = (((size_t)(j_g >> 3)) * 16 + m_g) * 8 + (j_g & 7);

  // ---- pipelined xz gather: prologue loads step-0's values ----
  int tk_cur = tok[(size_t)b_g * T];
  float x0, x1, x2, x3;
  {
    const float* ew = embW + (size_t)tk_cur * FH + j_g;
    x0 = ew[0]; x1 = ew[1024]; x2 = ew[2048]; x3 = ew[3072];
  }

  for (int t = 0; t < T; ++t) {
    // issue next-step token load early (1 dword; hides under poll sweep 1)
    const int tnx = (t + 1 < T) ? (t + 1) : (T - 1);
    const int tk_next = tok[(size_t)b_g * T + tnx];

    // ---- flag poll: hot spin, sc1 loads served fresh by local L2 ----
    {
      int fv, spins = 0;
      for (;;) {
        asm volatile("global_load_dword %0, %1, off sc0 sc1\n\t"
                     "s_waitcnt vmcnt(0)"
                     : "=v"(fv) : "v"(fpoll) : "memory");
        if (__all(fv >= t)) break;
        if (++spins > (1 << 17)) break;     // watchdog: never hang
        if (spins > 2048) __builtin_amdgcn_s_sleep(1);
      }
    }

    // ---- data: issue 8 coalesced loads, split-wait + MFMA interleave ----
    const u32x4* hb = ((t & 1) ? hB1 : hB0) + cbase;
    u32x4 e0, e1, e2, e3, e4, e5, e6, e7;
    asm volatile(
        "global_load_dwordx4 %0, %8, off sc0 sc1\n\t"
        "global_load_dwordx4 %1, %8, off offset:256 sc0 sc1\n\t"
        "global_load_dwordx4 %2, %8, off offset:512 sc0 sc1\n\t"
        "global_load_dwordx4 %3, %8, off offset:768 sc0 sc1\n\t"
        "global_load_dwordx4 %4, %8, off offset:1024 sc0 sc1\n\t"
        "global_load_dwordx4 %5, %8, off offset:1280 sc0 sc1\n\t"
        "global_load_dwordx4 %6, %8, off offset:1536 sc0 sc1\n\t"
        "global_load_dwordx4 %7, %8, off offset:1792 sc0 sc1"
        : "=&v"(e0), "=&v"(e1), "=&v"(e2), "=&v"(e3),
          "=&v"(e4), "=&v"(e5), "=&v"(e6), "=&v"(e7)
        : "v"(hb)
        : "memory");

    f32x4 acc[4];
#pragma unroll
    for (int nt = 0; nt < 4; ++nt) acc[nt] = (f32x4){0.f, 0.f, 0.f, 0.f};
#define MF(AH, KK)                                                                 \
  {                                                                                \
    _Pragma("unroll")                                                              \
    for (int nt = 0; nt < 4; ++nt)                                                 \
      acc[nt] = __builtin_amdgcn_mfma_f32_16x16x32_f16(AH, Bf[nt][KK], acc[nt], 0, 0, 0); \
  }
    asm volatile("s_waitcnt vmcnt(4)" ::: "memory");
    __builtin_amdgcn_sched_barrier(0);
    {
      const f16x8 a0 = __builtin_bit_cast(f16x8, e0);
      const f16x8 a1 = __builtin_bit_cast(f16x8, e1);
      const f16x8 a2 = __builtin_bit_cast(f16x8, e2);
      const f16x8 a3 = __builtin_bit_cast(f16x8, e3);
      MF(a0, 0) MF(a1, 1) MF(a2, 2) MF(a3, 3)
    }
    asm volatile("s_waitcnt vmcnt(0)" ::: "memory");
    __builtin_amdgcn_sched_barrier(0);
    {
      const f16x8 a4 = __builtin_bit_cast(f16x8, e4);
      const f16x8 a5 = __builtin_bit_cast(f16x8, e5);
      const f16x8 a6 = __builtin_bit_cast(f16x8, e6);
      const f16x8 a7 = __builtin_bit_cast(f16x8, e7);
      MF(a4, 4) MF(a5, 5) MF(a6, 6) MF(a7, 7)
    }
#undef MF

    // ---- prefetch next step's embW row (tok long since returned) ----
    float xn0, xn1, xn2, xn3;
    {
      const float* ewn = embW + (size_t)tk_next * FH + j_g;
      xn0 = ewn[0]; xn1 = ewn[1024]; xn2 = ewn[2048]; xn3 = ewn[3072];
    }

    // partial z -> LDS (f16, parity). D: col(n)=l15, row(m)=l4*4+r
    const int par = t & 1;
#pragma unroll
    for (int nt = 0; nt < 4; ++nt) {
      f16x4 v4;
#pragma unroll
      for (int r = 0; r < 4; ++r) v4[r] = (f16)acc[nt][r];
      *(f16x4*)&zph[par][kg][ng * 64 + nt * 16 + l15][l4 * 4] = v4;
    }
    __syncthreads();   // the ONLY barrier per step (RAW for gate reads)

    // ---- gate phase: 4 partials per gate (16 scalar LDS reads) ----
    float z0 = x0, z1 = x1, z2 = x2, z3 = x3;
#pragma unroll
    for (int q = 0; q < 4; ++q) {
      z0 += (float)zph[par][q][l_g][m_g];
      z1 += (float)zph[par][q][32 + l_g][m_g];
      z2 += (float)zph[par][q][64 + l_g][m_g];
      z3 += (float)zph[par][q][96 + l_g][m_g];
    }
    const float ig = fast_sigmoid(z0);
    const float fg = fast_sigmoid(z1);
    const float gg = fast_tanh(z2);
    const float og = fast_sigmoid(z3);
    const float cn = fg * c_st + ig * gg;
    const float hn = og * fast_tanh(cn);
    if (tk_cur != 0) { c_st = cn; h_st = hn; }   // masked hold in exact f32

    const f16 hv = (f16)h_st;

    // pack 8 neighbors' h into one f16x8 entry (4 shfls, r8/r13-verified)
    const u32 hbits = (u32)__builtin_bit_cast(unsigned short, hv);
    const u32 p  = hbits | ((u32)__shfl_xor((int)hbits, 1, 64) << 16);
    const u32 q2 = (u32)__shfl_xor((int)p, 2, 64);
    const u32 r2 = (u32)__shfl_xor((int)p, 4, 64);
    const u32 s2 = (u32)__shfl_xor((int)q2, 4, 64);
    if ((l_g & 7) == 0) {
      u32x4 val = {p, q2, r2, s2};
      u32x4* dst = ((t & 1) ? hB0 : hB1) + pidx;   // h_{t+1} -> buffer[(t+1)&1]
      if (FAST)                                    // plain: dirty in XCD L2
        asm volatile("global_store_dwordx4 %0, %1, off"
                     :: "v"(dst), "v"(val) : "memory");
      else
        asm volatile("global_store_dwordx4 %0, %1, off sc0 sc1"
                     :: "v"(dst), "v"(val) : "memory");
    }

    // per-wave release: drain this wave's entry stores, then epoch flag
    asm volatile("s_waitcnt vmcnt(0)" ::: "memory");
    if (lane == 0) {
      const int tv = t + 1;
      if (FAST)
        asm volatile("global_store_dword %0, %1, off"
                     :: "v"(pflag), "v"(tv) : "memory");
      else
        asm volatile("global_store_dword %0, %1, off sc0 sc1"
                     :: "v"(pflag), "v"(tv) : "memory");
    }

    // st store AFTER the signal: off the critical chain
    st[(size_t)(t * 8 + bg) * 16384 + stbase] = hv;

    // rotate the pipelined gather
    tk_cur = tk_next; x0 = xn0; x1 = xn1; x2 = xn2; x3 = xn3;
  }
}

// ---------------------------------------------------------------------------
// logits + softmax: row-groups rho = t*8+bg (4096 of 16 rows), 16 per block
__global__ __launch_bounds__(512, 2) void logits_kernel(
    const uint4* __restrict__ st, const uint4* __restrict__ wd,
    const float* __restrict__ bd, float* __restrict__ out)
{
  __shared__ f16 As[256 * 64];   // [rb 16][kc 8][m 16][e 8] = 32KB
  __shared__ f16 Bs[64 * 128];   // [nt 8][kkl 2][lane 64][e 8] = 16KB
  const int tid = threadIdx.x;
  const int w = tid >> 6, lane = tid & 63;
  const int l15 = lane & 15, l4 = lane >> 4;
  const int rblk0 = blockIdx.x * 16;

  f32x4 acc[2][8];
#pragma unroll
  for (int rb = 0; rb < 2; ++rb)
#pragma unroll
    for (int nt = 0; nt < 8; ++nt) acc[rb][nt] = (f32x4){0.f, 0.f, 0.f, 0.f};

  for (int ph = 0; ph < 16; ++ph) {        // k = ph*64 .. +64
    __syncthreads();
#pragma unroll
    for (int i = 0; i < 4; ++i) {          // A: 16 rb x 8 kc x 16 m chunks
      const int cc = tid * 4 + i;
      const int rb = cc >> 7, kc = (cc >> 4) & 7, m = cc & 15;
      ((uint4*)As)[cc] = st[((size_t)(rblk0 + rb) * 128 + ph * 8 + kc) * 16 + m];
    }
#pragma unroll
    for (int i = 0; i < 2; ++i) {          // B: 8 nt x 2 kkl x 64 chunks
      const int cc = tid * 2 + i;
      const int lc = cc & 63, kkl = (cc >> 6) & 1, nt = cc >> 7;
      ((uint4*)Bs)[cc] = wd[((size_t)nt * 32 + ph * 2 + kkl) * 64 + lc];
    }
    __syncthreads();
#pragma unroll
    for (int kkl = 0; kkl < 2; ++kkl)
#pragma unroll
      for (int rb = 0; rb < 2; ++rb) {
        const f16x8 a = ((const f16x8*)As)[((w * 2 + rb) * 8 + kkl * 4 + l4) * 16 + l15];
#pragma unroll
        for (int nt = 0; nt < 8; ++nt)
          acc[rb][nt] = __builtin_amdgcn_mfma_f32_16x16x32_f16(
              a, ((const f16x8*)Bs)[(nt * 2 + kkl) * 64 + lane], acc[rb][nt], 0, 0, 0);
      }
  }

  // epilogue: +bd, row softmax (row over 16 lanes x 8 nt), write f32
#pragma unroll
  for (int rb = 0; rb < 2; ++rb) {
    float mx[4] = {-3.0e38f, -3.0e38f, -3.0e38f, -3.0e38f};
#pragma unroll
    for (int nt = 0; nt < 8; ++nt) {
      const float bv = bd[nt * 16 + l15];
#pragma unroll
      for (int r = 0; r < 4; ++r) {
        acc[rb][nt][r] += bv;
        mx[r] = fmaxf(mx[r], acc[rb][nt][r]);
      }
    }
#pragma unroll
    for (int d = 1; d < 16; d <<= 1)
#pragma unroll
      for (int r = 0; r < 4; ++r) mx[r] = fmaxf(mx[r], __shfl_xor(mx[r], d, 64));
    float sm[4] = {0.f, 0.f, 0.f, 0.f};
#pragma unroll
    for (int nt = 0; nt < 8; ++nt)
#pragma unroll
      for (int r = 0; r < 4; ++r) {
        const float p = expf(acc[rb][nt][r] - mx[r]);
        acc[rb][nt][r] = p;
        sm[r] += p;
      }
#pragma unroll
    for (int d = 1; d < 16; d <<= 1)
#pragma unroll
      for (int r = 0; r < 4; ++r) sm[r] += __shfl_xor(sm[r], d, 64);
#pragma unroll
    for (int r = 0; r < 4; ++r) {
      const float inv = 1.f / sm[r];
      const int rg = (rblk0 + w * 2 + rb) * 16 + l4 * 4 + r;  // = t*128 + b
      const int bb = rg & 127, tt = rg >> 7;
      float* op = out + ((size_t)bb * T + tt) * V;
#pragma unroll
      for (int nt = 0; nt < 8; ++nt) op[nt * 16 + l15] = acc[rb][nt][r] * inv;
    }
  }
}

// ---------------------------------------------------------------------------
extern "C" void kernel_launch(void* const* d_in, const int* in_sizes, int n_in,
                              void* d_out, int out_size, void* d_ws, size_t ws_size,
                              hipStream_t stream) {
  const int*   tokens = (const int*)d_in[0];
  const float* emb    = (const float*)d_in[1];
  const float* W      = (const float*)d_in[2];
  const float* U      = (const float*)d_in[3];
  const float* bias   = (const float*)d_in[4];
  const float* Wd     = (const float*)d_in[5];
  const float* bd     = (const float*)d_in[6];
  float* out = (float*)d_out;
  char* ws = (char*)d_ws;

  if (ws_size < WS_NEED) {
    fprintf(stderr, "kernel_launch: ws too small: %zu < %zu\n", ws_size, WS_NEED);
    return;
  }

  int*   ctrl = (int*)(ws + OFF_CTRL);
  u32x4* hB0  = (u32x4*)(ws + OFF_HB0);
  u32x4* hB1  = (u32x4*)(ws + OFF_HB1);
  float* embW = (float*)(ws + OFF_EMBW);
  f16*   uf   = (f16*)(ws + OFF_UF);
  f16*   wdf  = (f16*)(ws + OFF_WD);
  f16*   st   = (f16*)(ws + OFF_ST);

  // zero ctrl (election + flags) and both entry parity buffers every launch
  (void)hipMemsetAsync(ws, 0, OFF_EMBW, stream);

  prep_embW<<<256, 256, 0, stream>>>(emb, W, bias, embW);
  prep_U<<<2048, 256, 0, stream>>>(U, uf);
  prep_Wd<<<64, 256, 0, stream>>>(Wd, wdf);

  lstm_kernel<<<256, 512, 0, stream>>>(tokens, embW, (const f16x8*)uf,
                                       hB0, hB1, st, ctrl);

  logits_kernel<<<256, 512, 0, stream>>>((const uint4*)st, (const uint4*)wdf,
                                         bd, out);
}